// Round 8
// baseline (39.405 us; speedup 1.0000x reference)
//
#include <hip/hip_runtime.h>

// Spatial transformer, bilinear sampling, NCHW fp32.
// X: (B, C, H, W) = (32, 3, 512, 512), theta: (B, 6), out: (B, C, H, W).
//
// R8: R7 (64-wide tiles, dwordx2 corner-pair gathers, L1 row reuse, nt
//     stores, XCD swizzle) + 2 px per thread in INDEPENDENT pipelines
//     (same column, rows r and r+4 of a 64x8 tile) -> 12 outstanding
//     gathers/thread to hide gather latency. Lane stride stays 4 B.

#define ST_H 512
#define ST_W 512
#define ST_C 3
#define ST_HW (ST_H * ST_W)

typedef float f2 __attribute__((ext_vector_type(2)));
struct __attribute__((packed, aligned(4))) f2_a4 { f2 v; };

__global__ __launch_bounds__(256) void st_bilinear_kernel(
    const float* __restrict__ X,
    const float* __restrict__ theta,
    float* __restrict__ out,
    int chunk)
{
    // XCD swizzle: each XCD owns a contiguous range of blocks (grid % 8 == 0).
    int bid = blockIdx.x;
    bid = (bid & 7) * chunk + (bid >> 3);

    const int b   = bid >> 9;             // 512 tiles per image (8 x, 64 y)
    const int idx = bid & 511;
    const int tx  = idx & 7;              // 8 tiles of 64 px across
    const int ty  = idx >> 3;             // 64 tiles of 8 rows down

    const int tid = (int)threadIdx.x;
    const int w  = (tx << 6) + (tid & 63);
    const int r  = tid >> 6;              // 0..3
    const int h1 = (ty << 3) + r;         // rows r and r+4 of the tile
    const int h2 = h1 + 4;

    const float* t = theta + b * 6;
    const float t00 = t[0], t01 = t[1], t02 = t[2];
    const float t10 = t[3], t11 = t[4], t12 = t[5];

    const float STEP = (float)(2.0 / 511.0);
    const float xg  = fmaf((float)w, STEP, -1.0f);      // shared (same col)
    const float xb0 = fmaf(t00, xg, t02);               // t00*xg + t02
    const float yb0 = fmaf(t10, xg, t12);

    const float* __restrict__ Xb = X + (size_t)b * (ST_C * ST_HW);
    float* __restrict__ ob = out + (size_t)b * (ST_C * ST_HW) + w;

#pragma unroll
    for (int k = 0; k < 2; ++k) {
        const int h = k ? h2 : h1;
        const float yg = fmaf((float)h, STEP, -1.0f);
        const float x = (fmaf(t01, yg, xb0) + 1.0f) * 256.0f;
        const float y = (fmaf(t11, yg, yb0) + 1.0f) * 256.0f;

        const int x0 = (int)floorf(x);
        const int y0 = (int)floorf(y);

        const int x0c = min(max(x0, 0), ST_W - 1);
        const int x1c = min(max(x0 + 1, 0), ST_W - 1);
        const int y0c = min(max(y0, 0), ST_H - 1);
        const int y1c = min(max(y0 + 1, 0), ST_H - 1);

        // weights use CLIPPED coords cast to float (reference semantics)
        const float x0f = (float)x0c, x1f = (float)x1c;
        const float y0f = (float)y0c, y1f = (float)y1c;
        const float wa = (x1f - x) * (y1f - y);
        const float wb = (x1f - x) * (y - y0f);
        const float wc = (x - x0f) * (y1f - y);
        const float wd = (x - x0f) * (y - y0f);

        // pair-gather start column; covers {x0c, x1c} for all clamp cases
        const int xa = min(max(x0, 0), ST_W - 2);
        const bool hi = (x0 >= ST_W - 1);
        const bool lo = (x0 < 0);

        const int ia = y0c * ST_W + xa;
        const int ib = y1c * ST_W + xa;

        float* __restrict__ o = ob + h * ST_W;
#pragma unroll
        for (int c = 0; c < ST_C; ++c) {
            const float* __restrict__ Xc = Xb + c * ST_HW;
            const f2 p = ((const f2_a4*)(Xc + ia))->v;   // (Ia, Ic)
            const f2 q = ((const f2_a4*)(Xc + ib))->v;   // (Ib, Id)
            const float Ia = hi ? p.y : p.x;
            const float Ic = lo ? p.x : p.y;
            const float Ib = hi ? q.y : q.x;
            const float Id = lo ? q.x : q.y;
            const float v = wa * Ia + wb * Ib + wc * Ic + wd * Id;
            // nontemporal: output has zero reuse; keep L1/L2 for the gathers
            __builtin_nontemporal_store(v, o + c * ST_HW);
        }
    }
}

extern "C" void kernel_launch(void* const* d_in, const int* in_sizes, int n_in,
                              void* d_out, int out_size, void* d_ws, size_t ws_size,
                              hipStream_t stream) {
    const float* X     = (const float*)d_in[0];
    const float* theta = (const float*)d_in[1];
    float* out         = (float*)d_out;

    const int B = in_sizes[1] / 6;          // 32
    const int block = 256;                  // 64x8 px tile, 2 px/thread
    const int grid = B * 512;               // 16384 blocks, divisible by 8
    const int chunk = grid / 8;             // blocks per XCD

    st_bilinear_kernel<<<grid, block, 0, stream>>>(X, theta, out, chunk);
}